// Round 12
// baseline (783.980 us; speedup 1.0000x reference)
//
#include <hip/hip_runtime.h>
#include <math.h>

// FORCE / RLS, round 15: r12's VERIFIED merged-spin structure (605us,
// absmax 0.015625) + vec4 gpart gather (the 4x request-rate cut), nothing
// else. Bounded spins retained.
//
// r14 post-mortem: absmax=NaN => sentinel/garbage passed the pipelined A1
// spin. Cause candidate: vmcnt(8) arithmetic is fragile — compiler scratch
// spills between the 9 asm loads and vm_wait8 also count toward vmcnt, so
// the wait can return with the h load still outstanding => hv read before
// completion => garbage defeats the sentinel check. This round uses ONLY
// vmcnt(0) waits (spill-immune), in exactly r12's loop shape.
//
// r12 already proved vec4 consumption of scalar-published data is safe
// (h is published as 16 scalar stores, consumed as dwordx4 — passed). So
// the only new element is gpart consumed as 8x dwordx4 per thread:
// thread (bg=tid>>5, sq=tid&31) gathers blocks bg*8..bg*8+7 at s-quad sq.
// Components with s>=t are masked from the sentinel check (never written).
// Accumulate: per-component b-ascending within group, then groups summed
// ascending in F1 — a reassociation of the same ascending block sum as r12
// (2-way split there); expected absmax drift <= 0.03, threshold 0.115.
//
// Implicit-P math (P0 = I, wO0 = 0):
//   k_t = h_t - sum_{s<t} d_s k_s,  g_s = k_s . h_t,  d_s = c_s g_s
//   c_t = 1/(1 + h.h - sum d_s g_s), z_t = -sum_{s<t} d_s e_s, e_t = z_t - y_t

#define NN   1024
#define TT   128
#define IDIM 16
#define ODIM 8
#define NBLK 64
#define NTHR 256
#define JPB  16
#define SENT 0xFFFFFFFFu
#define SPIN_MAX (1u << 20)   // bounded: diagnostic dead-latch, never hang

#define AL(p)    __hip_atomic_load((p), __ATOMIC_RELAXED, __HIP_MEMORY_SCOPE_AGENT)
#define AS(p, v) __hip_atomic_store((p), (v), __ATOMIC_RELAXED, __HIP_MEMORY_SCOPE_AGENT)

struct WS {
  float h[TT][NN];             // 512 KB, sentinel-initialized, written once
  float gpart[TT][NBLK][TT];   // 4 MB,   sentinel-initialized, written once
};

// Agent-coherent async loads (bypass L1+L2; caller issues vmcnt wait).
__device__ __forceinline__ float4 llc_load4_async(const float4* p) {
  float4 v;
  asm volatile("global_load_dwordx4 %0, %1, off sc0 sc1"
               : "=v"(v) : "v"(p) : "memory");
  return v;
}
__device__ __forceinline__ void vm_wait0() {
  asm volatile("s_waitcnt vmcnt(0)" ::: "memory");
  __builtin_amdgcn_sched_barrier(0);   // rule #18: pin the following checks
}

// ~32 dependent FMAs (~50ns): busy backoff between retry rounds.
__device__ __forceinline__ void spin_pause() {
  float a = 1.0f;
#pragma unroll
  for (int i = 0; i < 32; ++i) a = __builtin_fmaf(a, 1.0000001f, 1.0f);
  asm volatile("" :: "v"(a));   // keep the chain alive, no memory traffic
}

__device__ __forceinline__ int is_sent(float v) {
  return __float_as_uint(v) == SENT;
}
// bad iff any VALID component (s = 4*sq + c < t, i.e. c < nv) is sentinel
__device__ __forceinline__ bool vec_bad(const float4& v, int nv) {
  bool b = false;
  if (nv > 0) b |= (is_sent(v.x) != 0);
  if (nv > 1) b |= (is_sent(v.y) != 0);
  if (nv > 2) b |= (is_sent(v.z) != 0);
  if (nv > 3) b |= (is_sent(v.w) != 0);
  return b;
}

__global__ __launch_bounds__(NTHR, 1) void force_rls_kernel(
    const float* __restrict__ x, const float* __restrict__ y,
    const float* __restrict__ Win, const float* __restrict__ Wrec,
    const float* __restrict__ Wfb, float* __restrict__ out, WS* ws)
{
  const int tid  = threadIdx.x;
  const int bid  = blockIdx.x;
  const int lane = tid & 63;
  const int wv   = tid >> 6;
  const int j0   = bid * JPB;
  const int jj   = tid & 15;
  const int qq   = tid >> 4;
  const int sq   = tid & 31;    // s-quad index (s = 4*sq + c)
  const int bg   = tid >> 5;    // block-group (blocks bg*8 .. bg*8+7)
  const int sF   = tid & 127;   // epilogue slot index

  int dead = 0;                 // hardening latch: skip spins after timeout

  __shared__ float Ksl[TT][JPB];
  __shared__ float XW[TT][JPB];
  __shared__ float Ybuf[TT][ODIM];
  __shared__ float Ebuf[TT][ODIM];
  __shared__ float hfull[NN];
  __shared__ float cbuf[TT], dbuf[TT];
  __shared__ float Wfb_s[ODIM][JPB];
  __shared__ float Winsl[IDIM][JPB];
  __shared__ float redK[16][JPB], redM[16][JPB];
  __shared__ float redP[8][33][4];   // group partials (padded)
  __shared__ float redG[2][TT];      // epilogue only
  __shared__ float hcb[JPB], abuf[JPB], zbuf[ODIM];
  __shared__ float red2[4];
  __shared__ float sHH;

  // ---------------- init ----------------
  float4 w[16];
  {
    const int col = j0 + jj;
#pragma unroll
    for (int i = 0; i < 16; ++i) {
      const int r0 = (i << 6) + (qq << 2);
      w[i].x = Wrec[(size_t)(r0 + 0) * NN + col];
      w[i].y = Wrec[(size_t)(r0 + 1) * NN + col];
      w[i].z = Wrec[(size_t)(r0 + 2) * NN + col];
      w[i].w = Wrec[(size_t)(r0 + 3) * NN + col];
    }
  }
  { int i = tid >> 4, j = tid & 15; Winsl[i][j] = Win[i * NN + j0 + j]; }
  if (tid < ODIM * JPB) { int o = tid >> 4, j = tid & 15; Wfb_s[o][j] = Wfb[o * NN + j0 + j]; }
  for (int m = 0; m < (TT * ODIM) / NTHR; ++m) {
    int e = m * NTHR + tid; Ybuf[e >> 3][e & 7] = y[e];
  }
  if (tid < JPB) abuf[tid] = 0.f;
  if (tid < ODIM) zbuf[tid] = 0.f;
  __syncthreads();
  for (int m = 0; m < (TT * JPB) / NTHR; ++m) {
    int e = m * NTHR + tid; int t = e >> 4, j = e & 15;
    float s = 0.f;
#pragma unroll
    for (int i = 0; i < IDIM; ++i) s += x[t * IDIM + i] * Winsl[i][j];
    XW[t][j] = s;
  }
  __syncthreads();

  // ---------------- main loop: NO grid barrier, dataflow only ----------------
  for (int t = 0; t < TT; ++t) {
    // [A] MERGED spin (r12 structure): issue h (1 vec4) + gpart (8 vec4)
    //     together; one vmcnt(0) per retry round; reload only bad vectors.
    if (t >= 1) {
      const float* gbase = &ws->gpart[t - 1][0][0];
      const float4* hp = (const float4*)ws->h[t - 1] + tid;
      const int nv = t - 4 * sq;        // #valid comps in this quad (<=4)
      float4 gv[8];
      float4 hv = llc_load4_async(hp);
#pragma unroll
      for (int j = 0; j < 8; ++j) {
        const float* gp = gbase + (size_t)(bg * 8 + j) * TT + 4 * sq;
        gv[j] = llc_load4_async((const float4*)gp);
      }
      vm_wait0();
      unsigned rounds = 0u;
      for (;;) {
        bool hbad = is_sent(hv.x) || is_sent(hv.y) ||
                    is_sent(hv.z) || is_sent(hv.w);
        bool gbad = false;
        if (nv > 0) {
#pragma unroll
          for (int j = 0; j < 8; ++j) gbad |= vec_bad(gv[j], nv);
        }
        if (!__any((int)(hbad || gbad))) break;
        if (++rounds > SPIN_MAX) { dead = 1; break; }
        spin_pause();
        if (hbad) hv = llc_load4_async(hp);
        if (nv > 0) {
#pragma unroll
          for (int j = 0; j < 8; ++j) {
            if (vec_bad(gv[j], nv)) {
              const float* gp = gbase + (size_t)(bg * 8 + j) * TT + 4 * sq;
              gv[j] = llc_load4_async((const float4*)gp);
            }
          }
        }
        vm_wait0();
      }
      ((float4*)hfull)[tid] = hv;
      float4 acc;                       // b-ascending within the group
      acc.x = gv[0].x; acc.y = gv[0].y; acc.z = gv[0].z; acc.w = gv[0].w;
#pragma unroll
      for (int j = 1; j < 8; ++j) {
        acc.x += gv[j].x; acc.y += gv[j].y; acc.z += gv[j].z; acc.w += gv[j].w;
      }
      *(float4*)&redP[bg][sq][0] = acc; // garbage in comps s>=t: never read
    }
    __syncthreads();

    // [C1] matvec partials from REGISTER W (r6 order, bit-identical)
    float mp = 0.f;
    if (t >= 1) {
      const float4* hf4 = (const float4*)hfull;
#pragma unroll
      for (int i = 0; i < 16; ++i) {
        const int rb = (i << 6) + (qq << 2);
        const float4 hv = hf4[rb >> 2];
        mp += hv.x * w[i].x + hv.y * w[i].y + hv.z * w[i].z + hv.w * w[i].w;
      }
    }
    redM[qq][jj] = mp;

    // [F1] deferred reduce of step t-1: g_s (groups ascending), d_s, ||h||^2
    float dval = 0.f, gval = 0.f;
    if (t >= 1 && tid <= t - 1) {
      const int q = tid >> 2, c = tid & 3;
      float g = redP[0][q][c];
#pragma unroll
      for (int b = 1; b < 8; ++b) g += redP[b][q][c];
      gval = g;
      if (tid < t - 1) { dval = cbuf[tid] * g; dbuf[tid] = dval; }
      else sHH = g;
    }
    float s1p = dval * gval;
    s1p += __shfl_xor(s1p, 1, 64);
    s1p += __shfl_xor(s1p, 2, 64);
    s1p += __shfl_xor(s1p, 4, 64);
    s1p += __shfl_xor(s1p, 8, 64);
    s1p += __shfl_xor(s1p, 16, 64);
    s1p += __shfl_xor(s1p, 32, 64);
    if (lane == 0) red2[wv] = s1p;
    __syncthreads();

    // [F2] c_{t-1}, z_{t-1}, e_{t-1}   +   [B] K[t-1] partials
    if (t >= 1) {
      if (tid == 0) {
        float s1 = red2[0] + red2[1] + red2[2] + red2[3];
        cbuf[t - 1] = 1.f / (1.f + sHH - s1);
      }
      if (wv == 0) {                      // z_{t-1} = -sum_{s<t-1} d_s e_s
        const int o = lane & 7, gr8 = lane >> 3;
        float zp = 0.f;
        for (int s = gr8; s < t - 1; s += 8) zp += dbuf[s] * Ebuf[s][o];
        zp += __shfl_xor(zp, 8, 64);
        zp += __shfl_xor(zp, 16, 64);
        zp += __shfl_xor(zp, 32, 64);
        if (lane < 8) {
          float z = -zp;
          zbuf[o] = z;
          Ebuf[t - 1][o] = z - Ybuf[t - 1][o];
          if (bid == 0) out[(t - 1) * ODIM + o] = z;
        }
      }
    }
    float kp = 0.f;
    if (t >= 2) {
      for (int s = qq; s < t - 1; s += 16) kp -= dbuf[s] * Ksl[s][jj];
    }
    redK[qq][jj] = kp;
    __syncthreads();

    // [C2] combine -> a_t, h_t; finalize K[t-1]; publish h (fire-and-forget)
    if (tid < JPB) {
      const int j = tid;
      if (t >= 1) {
        float kv = hfull[j0 + j];
#pragma unroll
        for (int q = 0; q < 16; ++q) kv += redK[q][j];
        Ksl[t - 1][j] = kv;
      }
      float acc = 0.f;
#pragma unroll
      for (int q = 0; q < 16; ++q) acc += redM[q][j];
      float fb = 0.f;
#pragma unroll
      for (int o = 0; o < ODIM; ++o) fb += zbuf[o] * Wfb_s[o][j];
      float a = 0.9f * abuf[j] + 0.1f * (acc + XW[t][j] + fb);
      abuf[j] = a;
      float h = tanhf(a);
      hcb[j] = h;
      AS(&ws->h[t][j0 + j], h);
    }
    __syncthreads();

    // [D] publish g-partials of step t (fire-and-forget, word = flag)
    if (tid <= t) {
      float gp = 0.f;
      if (tid < t) {
#pragma unroll
        for (int j = 0; j < JPB; ++j) gp += Ksl[tid][j] * hcb[j];
      } else {
#pragma unroll
        for (int j = 0; j < JPB; ++j) gp += hcb[j] * hcb[j];
      }
      AS(&ws->gpart[t][bid][tid], gp);
    }
    // no drain, no flag, no barrier — consumers validate per-word
  }

  // ---------------- epilogue: z_127 -> out[127] (bid 0 only) ----------------
  if (bid == 0) {
    const int hf = tid >> 7;
    float ga = 0.f;
    if (sF < TT - 1) {
      const float* gq = &ws->gpart[TT - 1][hf * 32][0] + sF;
      float gvv[32];
#pragma unroll
      for (int b = 0; b < 32; ++b) gvv[b] = AL(gq + b * TT);
      unsigned rounds = 0u;
      for (;;) {
        bool bad = false;
#pragma unroll
        for (int b = 0; b < 32; ++b) bad |= (__float_as_uint(gvv[b]) == SENT);
        if (!bad || dead) break;
        if (++rounds > SPIN_MAX) { dead = 1; break; }
        spin_pause();
#pragma unroll
        for (int b = 0; b < 32; ++b)
          if (__float_as_uint(gvv[b]) == SENT) gvv[b] = AL(gq + b * TT);
      }
#pragma unroll
      for (int b = 0; b < 32; ++b) ga += gvv[b];
    }
    redG[hf][sF] = ga;
    __syncthreads();
    if (tid < TT - 1) dbuf[tid] = cbuf[tid] * (redG[0][tid] + redG[1][tid]);
    __syncthreads();
    if (wv == 0) {
      const int o = lane & 7, gr8 = lane >> 3;
      float zp = 0.f;
      for (int s = gr8; s < TT - 1; s += 8) zp += dbuf[s] * Ebuf[s][o];
      zp += __shfl_xor(zp, 8, 64);
      zp += __shfl_xor(zp, 16, 64);
      zp += __shfl_xor(zp, 32, 64);
      if (lane < 8) out[(TT - 1) * ODIM + o] = -zp;
    }
  }
}

extern "C" void kernel_launch(void* const* d_in, const int* in_sizes, int n_in,
                              void* d_out, int out_size, void* d_ws, size_t ws_size,
                              hipStream_t stream) {
  const float* x    = (const float*)d_in[0];
  const float* y    = (const float*)d_in[1];
  const float* Win  = (const float*)d_in[2];
  const float* Wrec = (const float*)d_in[3];
  const float* Wfb  = (const float*)d_in[4];
  // d_in[5] = wO (zeros), d_in[6] = P (identity): folded into implicit-P math.
  float* out = (float*)d_out;
  WS* ws = (WS*)d_ws;

  // Sentinel-fill the once-written dataflow buffers (0xFF bytes = NaN words).
  hipMemsetAsync(d_ws, 0xFF, sizeof(WS), stream);
  force_rls_kernel<<<NBLK, NTHR, 0, stream>>>(x, y, Win, Wrec, Wfb, out, ws);
}

// Round 13
// 671.415 us; speedup vs baseline: 1.1677x; 1.1677x over previous
//
#include <hip/hip_runtime.h>
#include <math.h>

// FORCE / RLS, round 16: r12 verbatim (best verified: 605us dispatch,
// absmax 0.015625) + out-stores moved OUT of the main loop.
//
// r15 post-mortem: vec4 gather (4x fewer requests, same bytes) was SLOWER
// (719us, FETCH up) -> request-rate/volume theories dead. r12's structure
// stands. Last identified per-step asymmetry: bid 0 issues 8 HBM-backed
// 'out' stores every step inside F2; their acks drain in bid0's next
// A-spin vmcnt(0). Since all blocks await all blocks each step, bid0's
// extra ack latency taxes the GLOBAL chain every step.
//
// Fix: z history accumulates in LDS zs[TT][ODIM] (uniform across blocks —
// also removes the bid==0 branch divergence in F2); bid 0 writes all
// 128x8 outputs as one float4 per thread in the epilogue. Arithmetic
// byte-identical to r12 -> absmax 0.015625.
//
// Implicit-P math (P0 = I, wO0 = 0):
//   k_t = h_t - sum_{s<t} d_s k_s,  g_s = k_s . h_t,  d_s = c_s g_s
//   c_t = 1/(1 + h.h - sum d_s g_s), z_t = -sum_{s<t} d_s e_s, e_t = z_t - y_t

#define NN   1024
#define TT   128
#define IDIM 16
#define ODIM 8
#define NBLK 64
#define NTHR 256
#define JPB  16
#define SENT 0xFFFFFFFFu
#define SPIN_MAX (1u << 20)   // bounded: diagnostic dead-latch, never hang

#define AL(p)    __hip_atomic_load((p), __ATOMIC_RELAXED, __HIP_MEMORY_SCOPE_AGENT)
#define AS(p, v) __hip_atomic_store((p), (v), __ATOMIC_RELAXED, __HIP_MEMORY_SCOPE_AGENT)

struct WS {
  float h[TT][NN];             // 512 KB, sentinel-initialized, written once
  float gpart[TT][NBLK][TT];   // 4 MB,   sentinel-initialized, written once
};

// Agent-coherent async loads (bypass L1+L2; caller issues vmcnt wait).
__device__ __forceinline__ float llc_load_async(const float* p) {
  float v;
  asm volatile("global_load_dword %0, %1, off sc0 sc1"
               : "=v"(v) : "v"(p) : "memory");
  return v;
}
__device__ __forceinline__ float4 llc_load4_async(const float4* p) {
  float4 v;
  asm volatile("global_load_dwordx4 %0, %1, off sc0 sc1"
               : "=v"(v) : "v"(p) : "memory");
  return v;
}
__device__ __forceinline__ void vm_wait0() {
  asm volatile("s_waitcnt vmcnt(0)" ::: "memory");
  __builtin_amdgcn_sched_barrier(0);   // rule #18: pin the following checks
}

// ~32 dependent FMAs (~50ns): busy backoff between retry rounds.
__device__ __forceinline__ void spin_pause() {
  float a = 1.0f;
#pragma unroll
  for (int i = 0; i < 32; ++i) a = __builtin_fmaf(a, 1.0000001f, 1.0f);
  asm volatile("" :: "v"(a));   // keep the chain alive, no memory traffic
}

__device__ __forceinline__ int is_sent(float v) {
  return __float_as_uint(v) == SENT;
}

__global__ __launch_bounds__(NTHR, 1) void force_rls_kernel(
    const float* __restrict__ x, const float* __restrict__ y,
    const float* __restrict__ Win, const float* __restrict__ Wrec,
    const float* __restrict__ Wfb, float* __restrict__ out, WS* ws)
{
  const int tid  = threadIdx.x;
  const int bid  = blockIdx.x;
  const int lane = tid & 63;
  const int wv   = tid >> 6;
  const int j0   = bid * JPB;
  const int jj   = tid & 15;
  const int qq   = tid >> 4;
  const int sF   = tid & 127;   // slot index for the g reduction
  const int hf   = tid >> 7;    // which half of the 64 blocks this thread sums

  int dead = 0;                 // hardening latch: skip spins after timeout

  __shared__ float Ksl[TT][JPB];
  __shared__ float XW[TT][JPB];
  __shared__ float Ybuf[TT][ODIM];
  __shared__ float Ebuf[TT][ODIM];
  __shared__ float zs[TT][ODIM];    // z history (out written in epilogue)
  __shared__ float hfull[NN];
  __shared__ float cbuf[TT], dbuf[TT];
  __shared__ float Wfb_s[ODIM][JPB];
  __shared__ float Winsl[IDIM][JPB];
  __shared__ float redK[16][JPB], redM[16][JPB];
  __shared__ float redG[2][TT];
  __shared__ float hcb[JPB], abuf[JPB], zbuf[ODIM];
  __shared__ float red2[4];
  __shared__ float sHH;

  // ---------------- init ----------------
  // Wrec slice -> registers: thread (qq,jj) owns rows r = 64*i + 4*qq + c of
  // column j0+jj. Same element-to-lane mapping as r6/r12.
  float4 w[16];
  {
    const int col = j0 + jj;
#pragma unroll
    for (int i = 0; i < 16; ++i) {
      const int r0 = (i << 6) + (qq << 2);
      w[i].x = Wrec[(size_t)(r0 + 0) * NN + col];
      w[i].y = Wrec[(size_t)(r0 + 1) * NN + col];
      w[i].z = Wrec[(size_t)(r0 + 2) * NN + col];
      w[i].w = Wrec[(size_t)(r0 + 3) * NN + col];
    }
  }
  { int i = tid >> 4, j = tid & 15; Winsl[i][j] = Win[i * NN + j0 + j]; }
  if (tid < ODIM * JPB) { int o = tid >> 4, j = tid & 15; Wfb_s[o][j] = Wfb[o * NN + j0 + j]; }
  for (int m = 0; m < (TT * ODIM) / NTHR; ++m) {
    int e = m * NTHR + tid; Ybuf[e >> 3][e & 7] = y[e];
  }
  if (tid < JPB) abuf[tid] = 0.f;
  if (tid < ODIM) zbuf[tid] = 0.f;
  __syncthreads();
  for (int m = 0; m < (TT * JPB) / NTHR; ++m) {
    int e = m * NTHR + tid; int t = e >> 4, j = e & 15;
    float s = 0.f;
#pragma unroll
    for (int i = 0; i < IDIM; ++i) s += x[t * IDIM + i] * Winsl[i][j];
    XW[t][j] = s;
  }
  __syncthreads();

  // ---------------- main loop: NO grid barrier, dataflow only ----------------
  for (int t = 0; t < TT; ++t) {
    // [A] MERGED spin (r12): issue gv + h together; one vmcnt(0) per retry
    //     round; reload only invalid words.
    if (t >= 1) {
      const float* gq = &ws->gpart[t - 1][hf * 32][0] + sF;
      const float4* hp = (const float4*)ws->h[t - 1] + tid;
      const bool gneed = (sF < t);
      float gv[32];
      float4 hv;
      if (gneed) {
#pragma unroll
        for (int b = 0; b < 32; ++b) gv[b] = llc_load_async(gq + b * TT);
      }
      hv = llc_load4_async(hp);
      vm_wait0();
      unsigned rounds = 0u;
      for (;;) {
        bool hbad = is_sent(hv.x) || is_sent(hv.y) ||
                    is_sent(hv.z) || is_sent(hv.w);
        bool gbad = false;
        if (gneed) {
#pragma unroll
          for (int b = 0; b < 32; ++b) gbad |= (is_sent(gv[b]) != 0);
        }
        if (!(hbad || gbad)) break;
        if (++rounds > SPIN_MAX) { dead = 1; break; }
        spin_pause();
        if (gneed) {
#pragma unroll
          for (int b = 0; b < 32; ++b)
            if (is_sent(gv[b])) gv[b] = llc_load_async(gq + b * TT);
        }
        if (hbad) hv = llc_load4_async(hp);
        vm_wait0();
      }
      float ga = 0.f;
      if (gneed) {
#pragma unroll
        for (int b = 0; b < 32; ++b) ga += gv[b];   // same order as r5/r6/r12
      }
      ((float4*)hfull)[tid] = hv;
      redG[hf][sF] = ga;                  // 0 for sF >= t (never read there)
    }
    __syncthreads();

    // [C1] matvec partials from REGISTER W (r6 order, bit-identical)
    float mp = 0.f;
    if (t >= 1) {
      const float4* hf4 = (const float4*)hfull;
#pragma unroll
      for (int i = 0; i < 16; ++i) {
        const int rb = (i << 6) + (qq << 2);
        const float4 hv = hf4[rb >> 2];
        mp += hv.x * w[i].x + hv.y * w[i].y + hv.z * w[i].z + hv.w * w[i].w;
      }
    }
    redM[qq][jj] = mp;

    // [F1] deferred reduce of step t-1: g_s, d_s, ||h||^2, Sigma d*g
    float dval = 0.f, gval = 0.f;
    if (t >= 1 && tid <= t - 1) {
      float g = redG[0][tid] + redG[1][tid];
      gval = g;
      if (tid < t - 1) { dval = cbuf[tid] * g; dbuf[tid] = dval; }
      else sHH = g;
    }
    float s1p = dval * gval;
    s1p += __shfl_xor(s1p, 1, 64);
    s1p += __shfl_xor(s1p, 2, 64);
    s1p += __shfl_xor(s1p, 4, 64);
    s1p += __shfl_xor(s1p, 8, 64);
    s1p += __shfl_xor(s1p, 16, 64);
    s1p += __shfl_xor(s1p, 32, 64);
    if (lane == 0) red2[wv] = s1p;
    __syncthreads();

    // [F2] c_{t-1}, z_{t-1}, e_{t-1}   +   [B] K[t-1] partials
    if (t >= 1) {
      if (tid == 0) {
        float s1 = red2[0] + red2[1] + red2[2] + red2[3];
        cbuf[t - 1] = 1.f / (1.f + sHH - s1);
      }
      if (wv == 0) {                      // z_{t-1} = -sum_{s<t-1} d_s e_s
        const int o = lane & 7, gr8 = lane >> 3;
        float zp = 0.f;
        for (int s = gr8; s < t - 1; s += 8) zp += dbuf[s] * Ebuf[s][o];
        zp += __shfl_xor(zp, 8, 64);
        zp += __shfl_xor(zp, 16, 64);
        zp += __shfl_xor(zp, 32, 64);
        if (lane < 8) {
          float z = -zp;
          zbuf[o] = z;
          Ebuf[t - 1][o] = z - Ybuf[t - 1][o];
          zs[t - 1][o] = z;               // LDS only — no HBM store in loop
        }
      }
    }
    float kp = 0.f;
    if (t >= 2) {
      for (int s = qq; s < t - 1; s += 16) kp -= dbuf[s] * Ksl[s][jj];
    }
    redK[qq][jj] = kp;
    __syncthreads();

    // [C2] combine -> a_t, h_t; finalize K[t-1]; publish h (fire-and-forget)
    if (tid < JPB) {
      const int j = tid;
      if (t >= 1) {
        float kv = hfull[j0 + j];
#pragma unroll
        for (int q = 0; q < 16; ++q) kv += redK[q][j];
        Ksl[t - 1][j] = kv;
      }
      float acc = 0.f;
#pragma unroll
      for (int q = 0; q < 16; ++q) acc += redM[q][j];
      float fb = 0.f;
#pragma unroll
      for (int o = 0; o < ODIM; ++o) fb += zbuf[o] * Wfb_s[o][j];
      float a = 0.9f * abuf[j] + 0.1f * (acc + XW[t][j] + fb);
      abuf[j] = a;
      float h = tanhf(a);
      hcb[j] = h;
      AS(&ws->h[t][j0 + j], h);
    }
    __syncthreads();

    // [D] publish g-partials of step t (fire-and-forget, word = flag)
    if (tid <= t) {
      float gp = 0.f;
      if (tid < t) {
#pragma unroll
        for (int j = 0; j < JPB; ++j) gp += Ksl[tid][j] * hcb[j];
      } else {
#pragma unroll
        for (int j = 0; j < JPB; ++j) gp += hcb[j] * hcb[j];
      }
      AS(&ws->gpart[t][bid][tid], gp);
    }
    // no drain, no flag, no barrier — consumers validate per-word
  }

  // ---------------- epilogue: z_127 + full out dump (bid 0 only) ----------------
  if (bid == 0) {
    float ga = 0.f;
    if (sF < TT - 1) {
      const float* gq = &ws->gpart[TT - 1][hf * 32][0] + sF;
      float gv[32];
#pragma unroll
      for (int b = 0; b < 32; ++b) gv[b] = AL(gq + b * TT);
      unsigned rounds = 0u;
      for (;;) {
        bool bad = false;
#pragma unroll
        for (int b = 0; b < 32; ++b) bad |= (__float_as_uint(gv[b]) == SENT);
        if (!bad || dead) break;
        if (++rounds > SPIN_MAX) { dead = 1; break; }
        spin_pause();
#pragma unroll
        for (int b = 0; b < 32; ++b)
          if (__float_as_uint(gv[b]) == SENT) gv[b] = AL(gq + b * TT);
      }
#pragma unroll
      for (int b = 0; b < 32; ++b) ga += gv[b];
    }
    redG[hf][sF] = ga;
    __syncthreads();
    if (tid < TT - 1) dbuf[tid] = cbuf[tid] * (redG[0][tid] + redG[1][tid]);
    __syncthreads();
    if (wv == 0) {
      const int o = lane & 7, gr8 = lane >> 3;
      float zp = 0.f;
      for (int s = gr8; s < TT - 1; s += 8) zp += dbuf[s] * Ebuf[s][o];
      zp += __shfl_xor(zp, 8, 64);
      zp += __shfl_xor(zp, 16, 64);
      zp += __shfl_xor(zp, 32, 64);
      if (lane < 8) zs[TT - 1][o] = -zp;
    }
    __syncthreads();
    // dump all 128x8 = 1024 floats: one float4 per thread, coalesced
    ((float4*)out)[tid] = ((const float4*)zs)[tid];
  }
}

extern "C" void kernel_launch(void* const* d_in, const int* in_sizes, int n_in,
                              void* d_out, int out_size, void* d_ws, size_t ws_size,
                              hipStream_t stream) {
  const float* x    = (const float*)d_in[0];
  const float* y    = (const float*)d_in[1];
  const float* Win  = (const float*)d_in[2];
  const float* Wrec = (const float*)d_in[3];
  const float* Wfb  = (const float*)d_in[4];
  // d_in[5] = wO (zeros), d_in[6] = P (identity): folded into implicit-P math.
  float* out = (float*)d_out;
  WS* ws = (WS*)d_ws;

  // Sentinel-fill the once-written dataflow buffers (0xFF bytes = NaN words).
  hipMemsetAsync(d_ws, 0xFF, sizeof(WS), stream);
  force_rls_kernel<<<NBLK, NTHR, 0, stream>>>(x, y, Win, Wrec, Wfb, out, ws);
}